// Round 4
// baseline (273.329 us; speedup 1.0000x reference)
//
#include <hip/hip_runtime.h>
#include <math.h>

#define H 1024
#define L 4096
#define V 29
#define NBLK 256
#define NTHR 256

#define AGENT __HIP_MEMORY_SCOPE_AGENT

__device__ __forceinline__ float aload(const float* p) {
    return __hip_atomic_load(const_cast<float*>(p), __ATOMIC_RELAXED, AGENT);
}
__device__ __forceinline__ void astore(float* p, float v) {
    __hip_atomic_store(p, v, __ATOMIC_RELAXED, AGENT);
}

__device__ __forceinline__ float waveReduceSum(float v) {
    #pragma unroll
    for (int off = 32; off > 0; off >>= 1)
        v += __shfl_down(v, off, 64);
    return v;
}

// Device-wide barrier among exactly-resident blocks (grid=256 <= 256 CUs).
// Distinct counter per barrier; arrive always, spin only if wait.
// Bounded spin: if co-residency were ever violated we return (bench fails
// loudly on absmax) instead of hanging the queue.
__device__ __forceinline__ void gridBarrier(unsigned int* c, bool wait) {
    __syncthreads();
    if (threadIdx.x == 0) {
        __threadfence();
        __hip_atomic_fetch_add(c, 1u, __ATOMIC_ACQ_REL, AGENT);
        if (wait) {
            long spins = 0;
            while (__hip_atomic_load(c, __ATOMIC_ACQUIRE, AGENT) < (unsigned)NBLK) {
                __builtin_amdgcn_s_sleep(2);
                if (++spins > 200000000L) break;   // hang valve (~seconds)
            }
            __threadfence();
        }
    }
    __syncthreads();
}

__global__ __launch_bounds__(NTHR) void fused_decoder(
    const int* __restrict__ tok, const float* __restrict__ h0,
    const float* __restrict__ c0, const float* __restrict__ enc,
    const float* __restrict__ emb, const float* __restrict__ attn_W,
    const float* __restrict__ attn_b, const float* __restrict__ comb_W,
    const float* __restrict__ comb_b, const float* __restrict__ W_ih,
    const float* __restrict__ W_hh, const float* __restrict__ b_ih,
    const float* __restrict__ b_hh, const float* __restrict__ out_W,
    const float* __restrict__ out_b, float* __restrict__ out,
    float* __restrict__ ws)
{
    __shared__ float4 sbuf[512];      // 8 KB phase staging (reused)
    __shared__ float sew[16];
    __shared__ float sinv;

    unsigned int* ctr = (unsigned int*)ws;   // [0..7] barrier counters (memset 0)
    float* denom    = ws + 8;                // fp32 softmax denominator (memset 0)
    float* attn_acc = ws + 16;               // 1024 (memset 0)
    float* e_ws     = ws + 1040;             // 4096
    float* hhg      = ws + 5136;             // 4096: h0.W_hh + b_ih + b_hh
    float* xbuf     = ws + 9232;             // 1024
    float* hnew     = ws + 10256;            // 1024
    float* lgts     = ws + 11280;            // 32

    const int tid = threadIdx.x, bid = blockIdx.x;
    const int wave = tid >> 6, lane = tid & 63;

    // ================= Phase 1: attn logits -> exp, and h0.W_hh =============
    const int t = tok[0];
    sbuf[tid]       = ((const float4*)(emb + (size_t)t * H))[tid];  // cat1 lo
    sbuf[256 + tid] = ((const float4*)h0)[tid];                     // cat1 hi
    __syncthreads();

    {
        float esum = 0.f;
        #pragma unroll
        for (int i = 0; i < 4; ++i) {
            const int row = bid * 16 + wave * 4 + i;            // 4096 rows
            const float4* wr = (const float4*)(attn_W + (size_t)row * (2 * H));
            float acc = 0.f;
            #pragma unroll
            for (int k = 0; k < 8; ++k) {
                float4 a = wr[k * 64 + lane];
                float4 b = sbuf[k * 64 + lane];
                acc += a.x * b.x + a.y * b.y + a.z * b.z + a.w * b.w;
            }
            acc = waveReduceSum(acc);
            if (lane == 0) {
                // |logit| <~ 5 (0.02-scale weights): exp safe w/o max-shift
                float e = __expf(acc + attn_b[row]);
                astore(&e_ws[row], e);
                esum += e;
            }
        }
        if (lane == 0) atomicAdd(denom, esum);

        #pragma unroll
        for (int i = 0; i < 4; ++i) {
            const int row = bid * 16 + wave * 4 + i;            // 4096 rows
            const float4* wr = (const float4*)(W_hh + (size_t)row * H);
            float acc = 0.f;
            #pragma unroll
            for (int k = 0; k < 4; ++k) {
                float4 a = wr[k * 64 + lane];
                float4 b = sbuf[256 + k * 64 + lane];
                acc += a.x * b.x + a.y * b.y + a.z * b.z + a.w * b.w;
            }
            acc = waveReduceSum(acc);
            if (lane == 0) astore(&hhg[row], acc + b_ih[row] + b_hh[row]);
        }
    }
    gridBarrier(ctr + 0, true);

    // ================= Phase 2: normalize + weighted encoder sum ============
    {
        if (tid == 0) sinv = 1.f / aload(denom);
        if (tid < 16) sew[tid] = aload(&e_ws[bid * 16 + tid]);
        __syncthreads();
        const float inv = sinv;
        float4 acc4 = make_float4(0.f, 0.f, 0.f, 0.f);
        #pragma unroll 4
        for (int r = 0; r < 16; ++r) {
            const int l = bid * 16 + r;
            const float w = sew[r] * inv;
            float4 ev = ((const float4*)(enc + (size_t)l * H))[tid];
            acc4.x += w * ev.x; acc4.y += w * ev.y;
            acc4.z += w * ev.z; acc4.w += w * ev.w;
        }
        if (tid < 16) out[V + 2 * H + bid * 16 + tid] = sew[tid] * inv; // attn_w
        const int c = tid * 4;
        atomicAdd(&attn_acc[c + 0], acc4.x);
        atomicAdd(&attn_acc[c + 1], acc4.y);
        atomicAdd(&attn_acc[c + 2], acc4.z);
        atomicAdd(&attn_acc[c + 3], acc4.w);
    }
    gridBarrier(ctr + 1, true);

    // ================= Phase 3: combine + relu ==============================
    {
        sbuf[tid] = ((const float4*)(emb + (size_t)t * H))[tid];
        float* s2 = (float*)(sbuf + 256);
        #pragma unroll
        for (int j = 0; j < 4; ++j)
            s2[tid + j * 256] = aload(&attn_acc[tid + j * 256]);
        __syncthreads();
        const int row = bid * 4 + wave;                         // 1024 rows
        const float4* wr = (const float4*)(comb_W + (size_t)row * (2 * H));
        float acc = 0.f;
        #pragma unroll
        for (int k = 0; k < 8; ++k) {
            float4 a = wr[k * 64 + lane];
            float4 b = sbuf[k * 64 + lane];
            acc += a.x * b.x + a.y * b.y + a.z * b.z + a.w * b.w;
        }
        acc = waveReduceSum(acc);
        if (lane == 0) astore(&xbuf[row], fmaxf(acc + comb_b[row], 0.f));
    }
    gridBarrier(ctr + 2, true);

    // ================= Phase 4: W_ih gates + LSTM elementwise ===============
    {
        float* xl = (float*)sbuf;
        #pragma unroll
        for (int j = 0; j < 4; ++j)
            xl[tid + j * 256] = aload(&xbuf[tid + j * 256]);
        __syncthreads();
        const int h = bid * 4 + wave;                           // hidden unit
        const float4* xv = (const float4*)xl;
        const float4* wi = (const float4*)(W_ih + (size_t)h * H);
        const float4* wf = (const float4*)(W_ih + (size_t)(H + h) * H);
        const float4* wg = (const float4*)(W_ih + (size_t)(2 * H + h) * H);
        const float4* wo = (const float4*)(W_ih + (size_t)(3 * H + h) * H);
        float ai = 0.f, af = 0.f, ag = 0.f, ao = 0.f;
        #pragma unroll
        for (int k = 0; k < 4; ++k) {
            float4 b = xv[k * 64 + lane];
            float4 a = wi[k * 64 + lane]; ai += a.x*b.x + a.y*b.y + a.z*b.z + a.w*b.w;
            float4 f = wf[k * 64 + lane]; af += f.x*b.x + f.y*b.y + f.z*b.z + f.w*b.w;
            float4 g = wg[k * 64 + lane]; ag += g.x*b.x + g.y*b.y + g.z*b.z + g.w*b.w;
            float4 o = wo[k * 64 + lane]; ao += o.x*b.x + o.y*b.y + o.z*b.z + o.w*b.w;
        }
        ai = waveReduceSum(ai); af = waveReduceSum(af);
        ag = waveReduceSum(ag); ao = waveReduceSum(ao);
        if (lane == 0) {
            const float gi = ai + aload(&hhg[h]);
            const float gf = af + aload(&hhg[H + h]);
            const float gg = ag + aload(&hhg[2 * H + h]);
            const float go = ao + aload(&hhg[3 * H + h]);
            const float c  = c0[h];
            const float si = 1.f / (1.f + __expf(-gi));
            const float sf = 1.f / (1.f + __expf(-gf));
            const float so = 1.f / (1.f + __expf(-go));
            const float cn = sf * c + si * tanhf(gg);
            const float hn = so * tanhf(cn);
            out[V + h]     = hn;
            out[V + H + h] = cn;
            astore(&hnew[h], hn);
        }
    }
    gridBarrier(ctr + 3, bid < V);          // only out-proj blocks wait

    // ================= Phase 5a: output projection (29 rows) ================
    if (bid < V) {
        float* hl = (float*)sbuf;
        #pragma unroll
        for (int j = 0; j < 4; ++j)
            hl[tid + j * 256] = aload(&hnew[tid + j * 256]);
        __syncthreads();
        if (wave == 0) {
            const float4* wr = (const float4*)(out_W + (size_t)bid * H);
            const float4* hv = (const float4*)hl;
            float acc = 0.f;
            #pragma unroll
            for (int k = 0; k < 4; ++k) {
                float4 a = wr[k * 64 + lane];
                float4 b = hv[k * 64 + lane];
                acc += a.x * b.x + a.y * b.y + a.z * b.z + a.w * b.w;
            }
            acc = waveReduceSum(acc);
            if (lane == 0) astore(&lgts[bid], acc + out_b[bid]);
        }
    }
    gridBarrier(ctr + 4, bid == 0);

    // ================= Phase 5b: log_softmax (block 0) ======================
    if (bid == 0 && tid < 64) {
        const float val = (tid < V) ? aload(&lgts[tid]) : -3.4e38f;
        float m = val;
        #pragma unroll
        for (int off = 32; off > 0; off >>= 1)
            m = fmaxf(m, __shfl_down(m, off, 64));
        m = __shfl(m, 0, 64);
        float e = (tid < V) ? __expf(val - m) : 0.f;
        float s = e;
        #pragma unroll
        for (int off = 32; off > 0; off >>= 1)
            s += __shfl_down(s, off, 64);
        s = __shfl(s, 0, 64);
        if (tid < V) out[tid] = val - m - logf(s);
    }
}

extern "C" void kernel_launch(void* const* d_in, const int* in_sizes, int n_in,
                              void* d_out, int out_size, void* d_ws, size_t ws_size,
                              hipStream_t stream) {
    const int*   tok    = (const int*)  d_in[0];
    const float* h0     = (const float*)d_in[1];
    const float* c0     = (const float*)d_in[2];
    const float* enc    = (const float*)d_in[3];
    const float* emb    = (const float*)d_in[4];
    const float* attn_W = (const float*)d_in[5];
    const float* attn_b = (const float*)d_in[6];
    const float* comb_W = (const float*)d_in[7];
    const float* comb_b = (const float*)d_in[8];
    const float* W_ih   = (const float*)d_in[9];
    const float* W_hh   = (const float*)d_in[10];
    const float* b_ih   = (const float*)d_in[11];
    const float* b_hh   = (const float*)d_in[12];
    const float* out_W  = (const float*)d_in[13];
    const float* out_b  = (const float*)d_in[14];
    float* out = (float*)d_out;
    float* ws  = (float*)d_ws;

    // Zero counters + denom + attn_acc ((16 + 1024) floats = 4160 bytes).
    hipMemsetAsync(ws, 0, (16 + 1024) * sizeof(float), stream);
    fused_decoder<<<NBLK, NTHR, 0, stream>>>(
        tok, h0, c0, enc, emb, attn_W, attn_b, comb_W, comb_b,
        W_ih, W_hh, b_ih, b_hh, out_W, out_b, out, ws);
}

// Round 5
// 196.778 us; speedup vs baseline: 1.3890x; 1.3890x over previous
//
#include <hip/hip_runtime.h>
#include <math.h>

#define H 1024
#define L 4096
#define V 29

__device__ __forceinline__ float waveReduceSum(float v) {
    #pragma unroll
    for (int off = 32; off > 0; off >>= 1)
        v += __shfl_down(v, off, 64);
    return v;
}

__device__ __forceinline__ float dot4(float4 a, float4 b) {
    return a.x * b.x + a.y * b.y + a.z * b.z + a.w * b.w;
}

// K1: blocks 0..1023: attn rows (4/block, 1/wave): e=exp(logit), blocksum[bid]
//     blocks 1024..2047: W_hh rows: hhg[r] = h0.W_hh[r] + b_ih[r] + b_hh[r]
//     block 0 zeroes attn_acc + fan-in counter (safe: K2 runs after K1).
// Deep-ILP: 8 float4 weight loads batched into registers before any use.
__global__ __launch_bounds__(256) void k1_logits_hh(
    const int* __restrict__ tok, const float* __restrict__ h0,
    const float* __restrict__ emb, const float* __restrict__ attn_W,
    const float* __restrict__ attn_b, const float* __restrict__ W_hh,
    const float* __restrict__ b_ih, const float* __restrict__ b_hh,
    float* __restrict__ e_ws, float* __restrict__ blocksum,
    float* __restrict__ hhg, float* __restrict__ attn_acc,
    unsigned int* __restrict__ ctr)
{
    __shared__ float4 sbuf[512];
    __shared__ float sred[4];
    const int tid = threadIdx.x, bid = blockIdx.x;
    const int wave = tid >> 6, lane = tid & 63;

    if (bid == 0) {
        ((float4*)attn_acc)[tid] = make_float4(0.f, 0.f, 0.f, 0.f);
        if (tid == 0) *ctr = 0u;
    }

    if (bid < 1024) {
        const int t = tok[0];
        sbuf[tid]       = ((const float4*)(emb + (size_t)t * H))[tid];
        sbuf[256 + tid] = ((const float4*)h0)[tid];

        const int row = bid * 4 + wave;
        const float4* wr = (const float4*)(attn_W + (size_t)row * (2 * H));
        float4 a[8];
        #pragma unroll
        for (int k = 0; k < 8; ++k) a[k] = wr[k * 64 + lane];  // 8 in flight
        __syncthreads();
        float acc = 0.f;
        #pragma unroll
        for (int k = 0; k < 8; ++k) acc += dot4(a[k], sbuf[k * 64 + lane]);
        acc = waveReduceSum(acc);
        if (lane == 0) {
            // |logit| <~ 5 with 0.02-scale weights: exp safe w/o max-shift
            float e = __expf(acc + attn_b[row]);
            e_ws[row] = e;
            sred[wave] = e;
        }
        __syncthreads();
        if (tid == 0) blocksum[bid] = sred[0] + sred[1] + sred[2] + sred[3];
    } else {
        sbuf[tid] = ((const float4*)h0)[tid];

        const int row = (bid - 1024) * 4 + wave;
        const float4* wr = (const float4*)(W_hh + (size_t)row * H);
        float4 a[4];
        #pragma unroll
        for (int k = 0; k < 4; ++k) a[k] = wr[k * 64 + lane];
        __syncthreads();
        float acc = 0.f;
        #pragma unroll
        for (int k = 0; k < 4; ++k) acc += dot4(a[k], sbuf[k * 64 + lane]);
        acc = waveReduceSum(acc);
        if (lane == 0) hhg[row] = acc + b_ih[row] + b_hh[row];
    }
}

// K2: redundant denom reduce (blocksum[1024], L2-hot) + weighted encoder sum
//     (two 8-deep load batches) + normalized attn_weights out.
__global__ __launch_bounds__(256) void k2_apply(
    const float* __restrict__ e_ws, const float* __restrict__ blocksum,
    const float* __restrict__ enc, float* __restrict__ attn_acc,
    float* __restrict__ attn_w_out)
{
    __shared__ float sred[4];
    __shared__ float sew[16];
    const int tid = threadIdx.x, bid = blockIdx.x;
    const int wave = tid >> 6, lane = tid & 63;

    float4 bs = ((const float4*)blocksum)[tid];
    if (tid < 16) sew[tid] = e_ws[bid * 16 + tid];
    float s = bs.x + bs.y + bs.z + bs.w;
    s = waveReduceSum(s);
    if (lane == 0) sred[wave] = s;
    __syncthreads();
    const float inv = 1.f / (sred[0] + sred[1] + sred[2] + sred[3]);

    float4 acc4 = make_float4(0.f, 0.f, 0.f, 0.f);
    {
        float4 e0[8];
        #pragma unroll
        for (int r = 0; r < 8; ++r)
            e0[r] = ((const float4*)(enc + (size_t)(bid * 16 + r) * H))[tid];
        #pragma unroll
        for (int r = 0; r < 8; ++r) {
            const float w = sew[r] * inv;
            acc4.x += w * e0[r].x; acc4.y += w * e0[r].y;
            acc4.z += w * e0[r].z; acc4.w += w * e0[r].w;
        }
        #pragma unroll
        for (int r = 0; r < 8; ++r)
            e0[r] = ((const float4*)(enc + (size_t)(bid * 16 + 8 + r) * H))[tid];
        #pragma unroll
        for (int r = 0; r < 8; ++r) {
            const float w = sew[8 + r] * inv;
            acc4.x += w * e0[r].x; acc4.y += w * e0[r].y;
            acc4.z += w * e0[r].z; acc4.w += w * e0[r].w;
        }
    }
    if (tid < 16) attn_w_out[bid * 16 + tid] = sew[tid] * inv;
    const int c = tid * 4;
    atomicAdd(&attn_acc[c + 0], acc4.x);
    atomicAdd(&attn_acc[c + 1], acc4.y);
    atomicAdd(&attn_acc[c + 2], acc4.z);
    atomicAdd(&attn_acc[c + 3], acc4.w);
}

// K3: x[row] = relu([emb, attn_applied] . comb_W[row] + comb_b[row])
__global__ __launch_bounds__(256) void k3_combine(
    const int* __restrict__ tok, const float* __restrict__ emb,
    const float* __restrict__ attn_acc, const float* __restrict__ comb_W,
    const float* __restrict__ comb_b, float* __restrict__ xbuf)
{
    __shared__ float4 sbuf[512];
    const int tid = threadIdx.x, bid = blockIdx.x;
    const int wave = tid >> 6, lane = tid & 63;
    const int t = tok[0];
    sbuf[tid]       = ((const float4*)(emb + (size_t)t * H))[tid];
    sbuf[256 + tid] = ((const float4*)attn_acc)[tid];

    const int row = bid * 4 + wave;                 // 256 blocks -> 1024 rows
    const float4* wr = (const float4*)(comb_W + (size_t)row * (2 * H));
    float4 a[8];
    #pragma unroll
    for (int k = 0; k < 8; ++k) a[k] = wr[k * 64 + lane];
    __syncthreads();
    float acc = 0.f;
    #pragma unroll
    for (int k = 0; k < 8; ++k) acc += dot4(a[k], sbuf[k * 64 + lane]);
    acc = waveReduceSum(acc);
    if (lane == 0) xbuf[row] = fmaxf(acc + comb_b[row], 0.f);
}

// K4: per wave: all 4 gate dots (16 loads batched) -> LSTM elementwise ->
//     h/c out. Last-finishing block: out-proj + log_softmax.
__global__ __launch_bounds__(256) void k4_gates_final(
    const float* __restrict__ xbuf, const float* __restrict__ c0,
    const float* __restrict__ W_ih, const float* __restrict__ hhg,
    const float* __restrict__ out_W, const float* __restrict__ out_b,
    float* __restrict__ hnew_ws, unsigned int* __restrict__ ctr,
    float* __restrict__ out)
{
    __shared__ float4 sx[256];
    __shared__ float logit[32];
    __shared__ bool amLast;
    const int tid = threadIdx.x, bid = blockIdx.x;  // 256 blocks
    const int wave = tid >> 6, lane = tid & 63;
    sx[tid] = ((const float4*)xbuf)[tid];

    const int h = bid * 4 + wave;                   // hidden unit
    float4 a[16];
    #pragma unroll
    for (int g = 0; g < 4; ++g) {
        const float4* wr = (const float4*)(W_ih + (size_t)(g * H + h) * H);
        #pragma unroll
        for (int k = 0; k < 4; ++k) a[g * 4 + k] = wr[k * 64 + lane];
    }
    __syncthreads();
    float ga[4];
    #pragma unroll
    for (int g = 0; g < 4; ++g) {
        float acc = 0.f;
        #pragma unroll
        for (int k = 0; k < 4; ++k) acc += dot4(a[g * 4 + k], sx[k * 64 + lane]);
        ga[g] = waveReduceSum(acc);
    }
    if (lane == 0) {
        const float gi = ga[0] + hhg[h];
        const float gf = ga[1] + hhg[H + h];
        const float gg = ga[2] + hhg[2 * H + h];
        const float go = ga[3] + hhg[3 * H + h];
        const float c  = c0[h];
        const float si = 1.f / (1.f + __expf(-gi));
        const float sf = 1.f / (1.f + __expf(-gf));
        const float so = 1.f / (1.f + __expf(-go));
        const float cn = sf * c + si * tanhf(gg);
        const float hn = so * tanhf(cn);
        out[V + h]     = hn;
        out[V + H + h] = cn;
        hnew_ws[h]     = hn;
    }

    // fan-in: last block to finish does the tiny output projection
    __threadfence();
    __syncthreads();
    if (tid == 0) amLast = (atomicAdd(ctr, 1u) == 255u);
    __syncthreads();
    if (amLast) {
        __threadfence();
        float* hn_l = (float*)sx;                   // reuse LDS, 1024 floats
        #pragma unroll
        for (int j = 0; j < 4; ++j) hn_l[tid + j * 256] = hnew_ws[tid + j * 256];
        __syncthreads();
        for (int v = wave; v < V; v += 4) {
            const float4* wr = (const float4*)(out_W + (size_t)v * H);
            float4 a2[4];
            #pragma unroll
            for (int k = 0; k < 4; ++k) a2[k] = wr[k * 64 + lane];
            float acc = 0.f;
            #pragma unroll
            for (int k = 0; k < 4; ++k)
                acc += dot4(a2[k], ((const float4*)hn_l)[k * 64 + lane]);
            acc = waveReduceSum(acc);
            if (lane == 0) logit[v] = acc + out_b[v];
        }
        __syncthreads();
        if (tid < 64) {
            const float val = (tid < V) ? logit[tid] : -3.4e38f;
            float m = val;
            #pragma unroll
            for (int off = 32; off > 0; off >>= 1)
                m = fmaxf(m, __shfl_down(m, off, 64));
            m = __shfl(m, 0, 64);
            float e = (tid < V) ? __expf(val - m) : 0.f;
            float s = e;
            #pragma unroll
            for (int off = 32; off > 0; off >>= 1)
                s += __shfl_down(s, off, 64);
            s = __shfl(s, 0, 64);
            if (tid < V) out[tid] = val - m - logf(s);
        }
    }
}

extern "C" void kernel_launch(void* const* d_in, const int* in_sizes, int n_in,
                              void* d_out, int out_size, void* d_ws, size_t ws_size,
                              hipStream_t stream) {
    const int*   tok    = (const int*)  d_in[0];
    const float* h0     = (const float*)d_in[1];
    const float* c0     = (const float*)d_in[2];
    const float* enc    = (const float*)d_in[3];
    const float* emb    = (const float*)d_in[4];
    const float* attn_W = (const float*)d_in[5];
    const float* attn_b = (const float*)d_in[6];
    const float* comb_W = (const float*)d_in[7];
    const float* comb_b = (const float*)d_in[8];
    const float* W_ih   = (const float*)d_in[9];
    const float* W_hh   = (const float*)d_in[10];
    const float* b_ih   = (const float*)d_in[11];
    const float* b_hh   = (const float*)d_in[12];
    const float* out_W  = (const float*)d_in[13];
    const float* out_b  = (const float*)d_in[14];

    float* out = (float*)d_out;
    float* ws  = (float*)d_ws;
    unsigned int* ctr = (unsigned int*)ws;  // 16 floats reserved
    float* blocksum = ws + 16;              // 1024
    float* e_ws     = ws + 1040;            // 4096
    float* hhg      = ws + 5136;            // 4096
    float* attn_acc = ws + 9232;            // 1024
    float* xbuf     = ws + 10256;           // 1024
    float* hnew_ws  = ws + 11280;           // 1024
    float* attn_w_out = out + V + 2 * H;    // attn_weights section

    k1_logits_hh<<<2048, 256, 0, stream>>>(tok, h0, emb, attn_W, attn_b,
                                           W_hh, b_ih, b_hh,
                                           e_ws, blocksum, hhg, attn_acc, ctr);
    k2_apply<<<256, 256, 0, stream>>>(e_ws, blocksum, enc, attn_acc, attn_w_out);
    k3_combine<<<256, 256, 0, stream>>>(tok, emb, attn_acc, comb_W, comb_b, xbuf);
    k4_gates_final<<<256, 256, 0, stream>>>(xbuf, c0, W_ih, hhg,
                                            out_W, out_b, hnew_ws, ctr, out);
}

// Round 6
// 173.713 us; speedup vs baseline: 1.5734x; 1.1328x over previous
//
#include <hip/hip_runtime.h>
#include <math.h>

#define H 1024
#define L 4096
#define V 29

__device__ __forceinline__ float waveReduceSum(float v) {
    #pragma unroll
    for (int off = 32; off > 0; off >>= 1)
        v += __shfl_down(v, off, 64);
    return v;
}

__device__ __forceinline__ float dot4(float4 a, float4 b) {
    return a.x * b.x + a.y * b.y + a.z * b.z + a.w * b.w;
}

// K1: attn logits -> e = exp(logit), per-block partial denom.
//     1024 blocks x 256 thr, one row per wave. Block 0 zeroes attn_acc.
__global__ __launch_bounds__(256) void k1_attn(
    const int* __restrict__ tok, const float* __restrict__ h0,
    const float* __restrict__ emb, const float* __restrict__ attn_W,
    const float* __restrict__ attn_b, float* __restrict__ e_ws,
    float* __restrict__ blocksum, float* __restrict__ attn_acc)
{
    __shared__ float4 sbuf[512];
    __shared__ float sred[4];
    const int tid = threadIdx.x, bid = blockIdx.x;
    const int wave = tid >> 6, lane = tid & 63;

    if (bid == 0) ((float4*)attn_acc)[tid] = make_float4(0.f, 0.f, 0.f, 0.f);

    const int t = tok[0];
    sbuf[tid]       = ((const float4*)(emb + (size_t)t * H))[tid];
    sbuf[256 + tid] = ((const float4*)h0)[tid];

    const int row = bid * 4 + wave;
    const float4* wr = (const float4*)(attn_W + (size_t)row * (2 * H));
    float4 a[8];
    #pragma unroll
    for (int k = 0; k < 8; ++k) a[k] = wr[k * 64 + lane];
    __syncthreads();
    float acc = 0.f;
    #pragma unroll
    for (int k = 0; k < 8; ++k) acc += dot4(a[k], sbuf[k * 64 + lane]);
    acc = waveReduceSum(acc);
    if (lane == 0) {
        // |logit| <~ 5 with 0.02-scale weights: exp safe w/o max-shift
        float e = __expf(acc + attn_b[row]);
        e_ws[row] = e;
        sred[wave] = e;
    }
    __syncthreads();
    if (tid == 0) blocksum[bid] = sred[0] + sred[1] + sred[2] + sred[3];
}

// K2: per-block redundant denom reduce (blocksum[1024], 4 KB) +
//     weighted encoder sum + normalized attn_weights out. 256 blocks.
__global__ __launch_bounds__(256) void k2_apply(
    const float* __restrict__ e_ws, const float* __restrict__ blocksum,
    const float* __restrict__ enc, float* __restrict__ attn_acc,
    float* __restrict__ attn_w_out)
{
    __shared__ float sred[4];
    __shared__ float sew[16];
    const int tid = threadIdx.x, bid = blockIdx.x;
    const int wave = tid >> 6, lane = tid & 63;

    float4 bs = ((const float4*)blocksum)[tid];
    if (tid < 16) sew[tid] = e_ws[bid * 16 + tid];
    float s = bs.x + bs.y + bs.z + bs.w;
    s = waveReduceSum(s);
    if (lane == 0) sred[wave] = s;
    __syncthreads();
    const float inv = 1.f / (sred[0] + sred[1] + sred[2] + sred[3]);

    float4 acc4 = make_float4(0.f, 0.f, 0.f, 0.f);
    {
        float4 e0[8];
        #pragma unroll
        for (int r = 0; r < 8; ++r)
            e0[r] = ((const float4*)(enc + (size_t)(bid * 16 + r) * H))[tid];
        #pragma unroll
        for (int r = 0; r < 8; ++r) {
            const float w = sew[r] * inv;
            acc4.x += w * e0[r].x; acc4.y += w * e0[r].y;
            acc4.z += w * e0[r].z; acc4.w += w * e0[r].w;
        }
        #pragma unroll
        for (int r = 0; r < 8; ++r)
            e0[r] = ((const float4*)(enc + (size_t)(bid * 16 + 8 + r) * H))[tid];
        #pragma unroll
        for (int r = 0; r < 8; ++r) {
            const float w = sew[8 + r] * inv;
            acc4.x += w * e0[r].x; acc4.y += w * e0[r].y;
            acc4.z += w * e0[r].z; acc4.w += w * e0[r].w;
        }
    }
    if (tid < 16) attn_w_out[bid * 16 + tid] = sew[tid] * inv;
    const int c = tid * 4;
    atomicAdd(&attn_acc[c + 0], acc4.x);
    atomicAdd(&attn_acc[c + 1], acc4.y);
    atomicAdd(&attn_acc[c + 2], acc4.z);
    atomicAdd(&attn_acc[c + 3], acc4.w);
}

// K3: x[row] = relu([emb, attn_applied] . comb_W[row] + comb_b[row])
//     256 blocks -> 1024 rows.
__global__ __launch_bounds__(256) void k3_combine(
    const int* __restrict__ tok, const float* __restrict__ emb,
    const float* __restrict__ attn_acc, const float* __restrict__ comb_W,
    const float* __restrict__ comb_b, float* __restrict__ xbuf)
{
    __shared__ float4 sbuf[512];
    const int tid = threadIdx.x, bid = blockIdx.x;
    const int wave = tid >> 6, lane = tid & 63;
    const int t = tok[0];
    sbuf[tid]       = ((const float4*)(emb + (size_t)t * H))[tid];
    sbuf[256 + tid] = ((const float4*)attn_acc)[tid];

    const int row = bid * 4 + wave;
    const float4* wr = (const float4*)(comb_W + (size_t)row * (2 * H));
    float4 a[8];
    #pragma unroll
    for (int k = 0; k < 8; ++k) a[k] = wr[k * 64 + lane];
    __syncthreads();
    float acc = 0.f;
    #pragma unroll
    for (int k = 0; k < 8; ++k) acc += dot4(a[k], sbuf[k * 64 + lane]);
    acc = waveReduceSum(acc);
    if (lane == 0) xbuf[row] = fmaxf(acc + comb_b[row], 0.f);
}

// K4: gates[r] = x.W_ih[r] + h0.W_hh[r] + b_ih[r] + b_hh[r]
//     1024 blocks, one row per wave (round-1 K5 structure).
__global__ __launch_bounds__(256) void k4_gates(
    const float* __restrict__ xbuf, const float* __restrict__ h0,
    const float* __restrict__ W_ih, const float* __restrict__ W_hh,
    const float* __restrict__ b_ih, const float* __restrict__ b_hh,
    float* __restrict__ gates)
{
    __shared__ float4 xs[256];
    __shared__ float4 hs[256];
    const int tid = threadIdx.x, bid = blockIdx.x;
    const int wave = tid >> 6, lane = tid & 63;
    xs[tid] = ((const float4*)xbuf)[tid];
    hs[tid] = ((const float4*)h0)[tid];

    const int row = bid * 4 + wave;
    const float4* wi = (const float4*)(W_ih + (size_t)row * H);
    const float4* wh = (const float4*)(W_hh + (size_t)row * H);
    float4 ai[4], ah[4];
    #pragma unroll
    for (int k = 0; k < 4; ++k) { ai[k] = wi[k * 64 + lane]; ah[k] = wh[k * 64 + lane]; }
    __syncthreads();
    float acc = 0.f;
    #pragma unroll
    for (int k = 0; k < 4; ++k) {
        acc += dot4(ai[k], xs[k * 64 + lane]);
        acc += dot4(ah[k], hs[k * 64 + lane]);
    }
    acc = waveReduceSum(acc);
    if (lane == 0) gates[row] = acc + b_ih[row] + b_hh[row];
}

// K5: LSTM elementwise + h/c writeback + out proj + log_softmax (1 block).
__global__ __launch_bounds__(1024) void k5_final(
    const float* __restrict__ gates, const float* __restrict__ c0,
    const float* __restrict__ out_W, const float* __restrict__ out_b,
    float* __restrict__ out)
{
    __shared__ float hnew[H];
    __shared__ float logit[32];
    const int tid = threadIdx.x;

    const float ig = gates[tid];
    const float fg = gates[H + tid];
    const float gg = gates[2 * H + tid];
    const float og = gates[3 * H + tid];
    const float c = c0[tid];
    const float si = 1.f / (1.f + __expf(-ig));
    const float sf = 1.f / (1.f + __expf(-fg));
    const float so = 1.f / (1.f + __expf(-og));
    const float cn = sf * c + si * tanhf(gg);
    const float hn = so * tanhf(cn);
    out[V + tid]     = hn;
    out[V + H + tid] = cn;
    hnew[tid] = hn;
    __syncthreads();

    const int wave = tid >> 6, lane = tid & 63;
    for (int v = wave; v < V; v += 16) {
        const float4* wr = (const float4*)(out_W + (size_t)v * H);
        float4 a[4];
        #pragma unroll
        for (int k = 0; k < 4; ++k) a[k] = wr[k * 64 + lane];
        float acc = 0.f;
        #pragma unroll
        for (int k = 0; k < 4; ++k)
            acc += dot4(a[k], ((const float4*)hnew)[k * 64 + lane]);
        acc = waveReduceSum(acc);
        if (lane == 0) logit[v] = acc + out_b[v];
    }
    __syncthreads();

    if (tid < 64) {
        const float val = (tid < V) ? logit[tid] : -3.4e38f;
        float m = val;
        #pragma unroll
        for (int off = 32; off > 0; off >>= 1)
            m = fmaxf(m, __shfl_down(m, off, 64));
        m = __shfl(m, 0, 64);
        float e = (tid < V) ? __expf(val - m) : 0.f;
        float s = e;
        #pragma unroll
        for (int off = 32; off > 0; off >>= 1)
            s += __shfl_down(s, off, 64);
        s = __shfl(s, 0, 64);
        if (tid < V) out[tid] = val - m - logf(s);
    }
}

extern "C" void kernel_launch(void* const* d_in, const int* in_sizes, int n_in,
                              void* d_out, int out_size, void* d_ws, size_t ws_size,
                              hipStream_t stream) {
    const int*   tok    = (const int*)  d_in[0];
    const float* h0     = (const float*)d_in[1];
    const float* c0     = (const float*)d_in[2];
    const float* enc    = (const float*)d_in[3];
    const float* emb    = (const float*)d_in[4];
    const float* attn_W = (const float*)d_in[5];
    const float* attn_b = (const float*)d_in[6];
    const float* comb_W = (const float*)d_in[7];
    const float* comb_b = (const float*)d_in[8];
    const float* W_ih   = (const float*)d_in[9];
    const float* W_hh   = (const float*)d_in[10];
    const float* b_ih   = (const float*)d_in[11];
    const float* b_hh   = (const float*)d_in[12];
    const float* out_W  = (const float*)d_in[13];
    const float* out_b  = (const float*)d_in[14];

    float* out = (float*)d_out;
    float* ws  = (float*)d_ws;
    float* blocksum = ws;                   // 1024
    float* e_ws     = ws + 1024;            // 4096
    float* attn_acc = ws + 5120;            // 1024
    float* xbuf     = ws + 6144;            // 1024
    float* gates    = ws + 7168;            // 4096
    float* attn_w_out = out + V + 2 * H;    // attn_weights section of d_out

    k1_attn<<<1024, 256, 0, stream>>>(tok, h0, emb, attn_W, attn_b,
                                      e_ws, blocksum, attn_acc);
    k2_apply<<<256, 256, 0, stream>>>(e_ws, blocksum, enc, attn_acc, attn_w_out);
    k3_combine<<<256, 256, 0, stream>>>(tok, emb, attn_acc, comb_W, comb_b, xbuf);
    k4_gates<<<1024, 256, 0, stream>>>(xbuf, h0, W_ih, W_hh, b_ih, b_hh, gates);
    k5_final<<<1, 1024, 0, stream>>>(gates, c0, out_W, out_b, out);
}